// Round 7
// baseline (10932.684 us; speedup 1.0000x reference)
//
#include <hip/hip_runtime.h>

#define D 128
#define NB 64
#define LBUF 96
#define T_STEPS 189

typedef __bf16 bf16x8 __attribute__((ext_vector_type(8)));
typedef float f32x4 __attribute__((ext_vector_type(4)));
typedef unsigned short u16x4v __attribute__((ext_vector_type(4)));
typedef unsigned short u16x8v __attribute__((ext_vector_type(8)));

// ---------------- ws layout (bytes) ----------------
// HEAP: bf16 rows of 128 (256B): row0 = zeros; row (1+ord*64+b) = comp h result
#define WS_HEAP   0u
// BUFH: bf16 rows: row0 = zeros; row (1+br*64+b) = h-half of buffers[br][b]
#define WS_BUFH   1541120u
#define WS_CC     3115008u     // float[94*64][128] comp c results
#define WS_XS     6195200u     // f16 [189][512 col][64 row] tracker static pre-acts
#define WS_CS     18581504u    // f16 [94 ord][640 col][64 row] comp static pre-acts
#define WS_WBUF   26281984u    // bf16 frag tables (B-operand layout)
#define WS_WS1    26413056u
#define WS_WS2    26544128u
#define WS_WHH    26675200u
#define WS_WL     26806272u
#define WS_WR     26970112u
#define WS_WT     27133952u
#define WS_THWS   27297792u    // bf16 [2][64][128] tracker-h ping-pong
#define WS_OFF1   27330560u    // u32[189*64] runtime-s1 heap offset (0=static->zero row)
#define WS_OFF2   27378944u
#define WS_BOFF   27427328u    // u32[189*64] buf-top offset into BUFH
#define WS_S1B    27475712u    // u32[189*64] static-s1 offset into BUFH (0=runtime->zero row)
#define WS_S2B    27524096u
#define WS_COF1   27572480u    // u32[189*64] comp s1-c source (bit31: 1=CC, 0=buffers), byte off
#define WS_COF2   27620864u
#define WS_RORD   27669248u    // i32[189*64] reduce ordinal or -1
#define WS_SFLG   27717632u    // u32[189] step flags: 1=any rt s1, 2=any rt s2, 4=any reduce
#define WS_OSRC   27718400u    // u32[64] final top source (bit31: 1=HEAP, 0=BUFH), byte off

#define RTAG 0x40000000
#define TMSK 0x3fffffff

__device__ __forceinline__ unsigned short f2bf(float f){
  unsigned x = __builtin_bit_cast(unsigned, f);
  unsigned r = (x + 0x7fffu + ((x >> 16) & 1u)) >> 16;
  return (unsigned short)r;
}
__device__ __forceinline__ float bf2f(unsigned short u){
  unsigned x = ((unsigned)u) << 16;
  return __builtin_bit_cast(float, x);
}
__device__ __forceinline__ unsigned short f2h(float x){
  _Float16 h = (_Float16)x;
  return __builtin_bit_cast(unsigned short, h);
}
__device__ __forceinline__ float h2f(unsigned short u){
  return (float)__builtin_bit_cast(_Float16, u);
}
__device__ __forceinline__ float sigf(float x){ return 1.f / (1.f + __expf(-x)); }
__device__ __forceinline__ float tanhf_(float x){ return 1.f - 2.f / (__expf(2.f * x) + 1.f); }

// ============ K0: symbolic stack simulation (1 wave, 1 thread per row) ============
__global__ void k0_sim(const int* __restrict__ trans, unsigned char* __restrict__ ws){
  __shared__ int tag[64][99];
  const int b = threadIdx.x;
  unsigned* OFF1 = (unsigned*)(ws + WS_OFF1);
  unsigned* OFF2 = (unsigned*)(ws + WS_OFF2);
  unsigned* BOFF = (unsigned*)(ws + WS_BOFF);
  unsigned* S1B  = (unsigned*)(ws + WS_S1B);
  unsigned* S2B  = (unsigned*)(ws + WS_S2B);
  unsigned* COF1 = (unsigned*)(ws + WS_COF1);
  unsigned* COF2 = (unsigned*)(ws + WS_COF2);
  int*      RORD = (int*)(ws + WS_RORD);
  unsigned* SFLG = (unsigned*)(ws + WS_SFLG);
  unsigned* OSRC = (unsigned*)(ws + WS_OSRC);

  tag[b][0] = 0; tag[b][1] = 0;      // sentinel = buffer row 0 (static)
  int sp = 2, bp = LBUF, rc = 0;
  for (int t = 0; t < T_STEPS; ++t){
    int tr = trans[t * 64 + b];
    int s1 = tag[b][sp - 1], s2 = tag[b][sp - 2];
    int bt = bp - 1;
    int r1 = (s1 & RTAG) != 0, r2 = (s2 & RTAG) != 0;
    int ix = t * 64 + b;
    OFF1[ix] = r1 ? (unsigned)((1 + (s1 & TMSK) * 64 + b) * 256) : 0u;
    OFF2[ix] = r2 ? (unsigned)((1 + (s2 & TMSK) * 64 + b) * 256) : 0u;
    BOFF[ix] = (unsigned)((1 + bt * 64 + b) * 256);
    S1B[ix]  = r1 ? 0u : (unsigned)((1 + s1 * 64 + b) * 256);
    S2B[ix]  = r2 ? 0u : (unsigned)((1 + s2 * 64 + b) * 256);
    int red = (tr == 2), sh = (tr == 3);
    unsigned f = (__any(r1) ? 1u : 0u) | (__any(r2) ? 2u : 0u) | (__any(red) ? 4u : 0u);
    if (b == 0) SFLG[t] = f;
    unsigned c1 = 0, c2 = 0; int ro = -1;
    if (red){
      ro = rc++;
      c1 = r1 ? (0x80000000u | (unsigned)((((s1 & TMSK) * 64 + b)) << 9))
              : (unsigned)((s1 * 64 + b) * 1024 + 512);
      c2 = r2 ? (0x80000000u | (unsigned)((((s2 & TMSK) * 64 + b)) << 9))
              : (unsigned)((s2 * 64 + b) * 1024 + 512);
      tag[b][sp - 2] = RTAG | ro;
      sp -= 1;
    } else if (sh){
      tag[b][sp] = bt; sp++; bp--;
    }
    COF1[ix] = c1; COF2[ix] = c2; RORD[ix] = ro;
  }
  int top = tag[b][sp - 1];
  OSRC[b] = (top & RTAG) ? (0x80000000u | (unsigned)((1 + (top & TMSK) * 64 + b) * 256))
                         : (unsigned)((1 + top * 64 + b) * 256);
}

// ============ K1: weight frag tables + bufh + zero rows (parallel) ============
__global__ __launch_bounds__(256) void k1_prep(
    const float* __restrict__ buffers, const float* __restrict__ W_ih,
    const float* __restrict__ W_hh, const float* __restrict__ Wl,
    const float* __restrict__ Wr, const float* __restrict__ Wt,
    unsigned char* __restrict__ ws)
{
  // frag tables: elem e -> j=e&7, l=(e>>3)&63, kt=(e>>9)&3, nt=e>>11
  // value = SRC[(nt*16+(l&15))*LD + KO + kt*32 + (l>>4)*8 + j]
  const int gid = blockIdx.x * 256 + threadIdx.x;
  const int gsz = gridDim.x * 256;
  const int NWB = 507904;                 // 4*65536 + 3*81920
  const int NBU = 6145 * 128;             // BUFH rows (incl zero row)
  for (int i = gid; i < NWB + NBU + 128 + 16384; i += gsz){
    if (i < NWB){
      int e = i; const float* src; unsigned dst; int LD, KO;
      if      (e < 65536)  { src = W_ih; dst = WS_WBUF; LD = 384; KO = 0; }
      else if (e < 131072) { src = W_ih; dst = WS_WS1;  LD = 384; KO = 128; e -= 65536; }
      else if (e < 196608) { src = W_ih; dst = WS_WS2;  LD = 384; KO = 256; e -= 131072; }
      else if (e < 262144) { src = W_hh; dst = WS_WHH;  LD = 128; KO = 0;   e -= 196608; }
      else if (e < 344064) { src = Wl;   dst = WS_WL;   LD = 128; KO = 0;   e -= 262144; }
      else if (e < 425984) { src = Wr;   dst = WS_WR;   LD = 128; KO = 0;   e -= 344064; }
      else                 { src = Wt;   dst = WS_WT;   LD = 128; KO = 0;   e -= 425984; }
      int j = e & 7, l = (e >> 3) & 63, kt = (e >> 9) & 3, nt = e >> 11;
      float v = src[(nt * 16 + (l & 15)) * LD + KO + kt * 32 + (l >> 4) * 8 + j];
      *(unsigned short*)(ws + dst + (size_t)e * 2) = f2bf(v);
    } else if (i < NWB + NBU){
      int e = i - NWB; int row = e >> 7, k = e & 127;
      unsigned short v = (row == 0) ? (unsigned short)0
                                    : f2bf(buffers[(size_t)(row - 1) * 256 + k]);
      *(unsigned short*)(ws + WS_BUFH + (size_t)e * 2) = v;
    } else if (i < NWB + NBU + 128){
      int k = i - NWB - NBU;
      *(unsigned short*)(ws + WS_HEAP + k * 2) = 0;   // heap zero row
    } else {
      int k = i - NWB - NBU - 128;
      *(unsigned short*)(ws + WS_THWS + k * 2) = 0;   // th ping-pong buffers
    }
  }
}

// ============ K2: XS[t] static tracker pre-acts (189 WGs) ============
__global__ __launch_bounds__(256, 1) void k2_xs(
    const float* __restrict__ b_ih, const float* __restrict__ b_hh,
    unsigned char* __restrict__ ws)
{
  const int tid = threadIdx.x, l = tid & 63, w = tid >> 6, t = blockIdx.x;
  const int ko = (l >> 4) * 8;
  unsigned ob[4], o1[4], o2[4];
  #pragma unroll
  for (int mt = 0; mt < 4; ++mt){
    int r = mt * 16 + (l & 15);
    ob[mt] = *(const unsigned*)(ws + WS_BOFF + (t * 64 + r) * 4);
    o1[mt] = *(const unsigned*)(ws + WS_S1B  + (t * 64 + r) * 4);
    o2[mt] = *(const unsigned*)(ws + WS_S2B  + (t * 64 + r) * 4);
  }
  bf16x8 aB[4][4], a1[4][4], a2[4][4];
  #pragma unroll
  for (int mt = 0; mt < 4; ++mt)
    #pragma unroll
    for (int kt = 0; kt < 4; ++kt){
      aB[mt][kt] = *(const bf16x8*)(ws + WS_BUFH + ob[mt] + (kt * 32 + ko) * 2);
      a1[mt][kt] = *(const bf16x8*)(ws + WS_BUFH + o1[mt] + (kt * 32 + ko) * 2);
      a2[mt][kt] = *(const bf16x8*)(ws + WS_BUFH + o2[mt] + (kt * 32 + ko) * 2);
    }
  for (int i = 0; i < 8; ++i){
    int nt = w * 8 + i;
    f32x4 acc[4];
    #pragma unroll
    for (int mt = 0; mt < 4; ++mt) acc[mt] = (f32x4){0.f, 0.f, 0.f, 0.f};
    #pragma unroll
    for (int kt = 0; kt < 4; ++kt){
      bf16x8 bB = *(const bf16x8*)(ws + WS_WBUF + ((nt * 4 + kt) * 64 + l) * 16);
      #pragma unroll
      for (int mt = 0; mt < 4; ++mt) acc[mt] = __builtin_amdgcn_mfma_f32_16x16x32_bf16(aB[mt][kt], bB, acc[mt], 0, 0, 0);
    }
    #pragma unroll
    for (int kt = 0; kt < 4; ++kt){
      bf16x8 bB = *(const bf16x8*)(ws + WS_WS1 + ((nt * 4 + kt) * 64 + l) * 16);
      #pragma unroll
      for (int mt = 0; mt < 4; ++mt) acc[mt] = __builtin_amdgcn_mfma_f32_16x16x32_bf16(a1[mt][kt], bB, acc[mt], 0, 0, 0);
    }
    #pragma unroll
    for (int kt = 0; kt < 4; ++kt){
      bf16x8 bB = *(const bf16x8*)(ws + WS_WS2 + ((nt * 4 + kt) * 64 + l) * 16);
      #pragma unroll
      for (int mt = 0; mt < 4; ++mt) acc[mt] = __builtin_amdgcn_mfma_f32_16x16x32_bf16(a2[mt][kt], bB, acc[mt], 0, 0, 0);
    }
    int col = nt * 16 + (l & 15);
    float bv = b_ih[col] + b_hh[col];
    #pragma unroll
    for (int mt = 0; mt < 4; ++mt){
      u16x4v pk;
      #pragma unroll
      for (int j = 0; j < 4; ++j) pk[j] = f2h(acc[mt][j] + bv);
      *(u16x4v*)(ws + WS_XS + ((size_t)((t * 512 + col) * 64) + 16 * mt + 4 * (l >> 4)) * 2) = pk;
    }
  }
}

// ============ K2b: CS[ord] static comp pre-acts (189 WGs, reduce steps) ============
__global__ __launch_bounds__(256, 1) void k2b_cs(
    const float* __restrict__ bl, unsigned char* __restrict__ ws)
{
  const int t = blockIdx.x;
  unsigned fl = *(const unsigned*)(ws + WS_SFLG + t * 4);
  if (!(fl & 4u)) return;
  const int tid = threadIdx.x, l = tid & 63, w = tid >> 6;
  const int ko = (l >> 4) * 8;
  unsigned o1[4], o2[4];
  int rord[4][4];
  #pragma unroll
  for (int mt = 0; mt < 4; ++mt){
    int r = mt * 16 + (l & 15);
    o1[mt] = *(const unsigned*)(ws + WS_S1B + (t * 64 + r) * 4);
    o2[mt] = *(const unsigned*)(ws + WS_S2B + (t * 64 + r) * 4);
    #pragma unroll
    for (int j = 0; j < 4; ++j)
      rord[mt][j] = *(const int*)(ws + WS_RORD + (t * 64 + mt * 16 + 4 * (l >> 4) + j) * 4);
  }
  bf16x8 a1[4][4], a2[4][4];
  #pragma unroll
  for (int mt = 0; mt < 4; ++mt)
    #pragma unroll
    for (int kt = 0; kt < 4; ++kt){
      a1[mt][kt] = *(const bf16x8*)(ws + WS_BUFH + o1[mt] + (kt * 32 + ko) * 2);
      a2[mt][kt] = *(const bf16x8*)(ws + WS_BUFH + o2[mt] + (kt * 32 + ko) * 2);
    }
  for (int i = 0; i < 10; ++i){
    int nt = w * 10 + i;
    f32x4 acc[4];
    #pragma unroll
    for (int mt = 0; mt < 4; ++mt) acc[mt] = (f32x4){0.f, 0.f, 0.f, 0.f};
    #pragma unroll
    for (int kt = 0; kt < 4; ++kt){
      bf16x8 bR = *(const bf16x8*)(ws + WS_WR + ((nt * 4 + kt) * 64 + l) * 16);
      #pragma unroll
      for (int mt = 0; mt < 4; ++mt) acc[mt] = __builtin_amdgcn_mfma_f32_16x16x32_bf16(a1[mt][kt], bR, acc[mt], 0, 0, 0);
    }
    #pragma unroll
    for (int kt = 0; kt < 4; ++kt){
      bf16x8 bL = *(const bf16x8*)(ws + WS_WL + ((nt * 4 + kt) * 64 + l) * 16);
      #pragma unroll
      for (int mt = 0; mt < 4; ++mt) acc[mt] = __builtin_amdgcn_mfma_f32_16x16x32_bf16(a2[mt][kt], bL, acc[mt], 0, 0, 0);
    }
    int col = nt * 16 + (l & 15);
    float bv = bl[col];
    #pragma unroll
    for (int mt = 0; mt < 4; ++mt)
      #pragma unroll
      for (int j = 0; j < 4; ++j){
        int od = rord[mt][j];
        if (od >= 0){
          int row = mt * 16 + 4 * (l >> 4) + j;
          *(unsigned short*)(ws + WS_CS + ((size_t)(od * 640 + col) * 64 + row) * 2) = f2h(acc[mt][j] + bv);
        }
      }
  }
}

// ============ K3: the serial chain (ONE workgroup, 4 waves) ============
__global__ __launch_bounds__(256, 1) void k3_serial(
    const float* __restrict__ buffers, float* __restrict__ out,
    unsigned char* __restrict__ ws)
{
  extern __shared__ unsigned short smem[];   // 131072 B = W_hh frag table
  const int tid = threadIdx.x, l = tid & 63, w = tid >> 6;
  const int ko = (l >> 4) * 8;

  // stage W_hh frags into LDS (128 KiB exact)
  for (int i = tid * 8; i < 65536; i += 2048)
    *(u16x8v*)(smem + i) = *(const u16x8v*)(ws + WS_WHH + (size_t)i * 2);

  // resident W_s1 / W_s2 frags (wave w owns tracker dims 32w..32w+31)
  bf16x8 ws1f[4][2][4], ws2f[4][2][4];
  #pragma unroll
  for (int g = 0; g < 4; ++g)
    #pragma unroll
    for (int hn = 0; hn < 2; ++hn)
      #pragma unroll
      for (int kt = 0; kt < 4; ++kt){
        int nt = g * 8 + 2 * w + hn;
        ws1f[g][hn][kt] = *(const bf16x8*)(ws + WS_WS1 + ((nt * 4 + kt) * 64 + l) * 16);
        ws2f[g][hn][kt] = *(const bf16x8*)(ws + WS_WS2 + ((nt * 4 + kt) * 64 + l) * 16);
      }
  float tcr[4][2][4];
  #pragma unroll
  for (int q = 0; q < 4; ++q)
    #pragma unroll
    for (int hn = 0; hn < 2; ++hn)
      #pragma unroll
      for (int j = 0; j < 4; ++j) tcr[q][hn][j] = 0.f;

  __syncthreads();

  for (int t = 0; t < T_STEPS; ++t){
    const unsigned fl = __builtin_amdgcn_readfirstlane(*(const unsigned*)(ws + WS_SFLG + t * 4));
    unsigned short* th_rd = (unsigned short*)(ws + WS_THWS) + (t & 1) * 8192;
    unsigned short* th_wr = (unsigned short*)(ws + WS_THWS) + ((t + 1) & 1) * 8192;

    // ---------- tracker: 4 row-quarters ----------
    for (int q = 0; q < 4; ++q){
      const int rq = q * 16 + (l & 15);
      u16x4v xsv[4][2];
      #pragma unroll
      for (int g = 0; g < 4; ++g)
        #pragma unroll
        for (int hn = 0; hn < 2; ++hn){
          int col = (g * 8 + 2 * w + hn) * 16 + (l & 15);
          xsv[g][hn] = *(const u16x4v*)(ws + WS_XS + ((size_t)((t * 512 + col) * 64) + q * 16 + 4 * (l >> 4)) * 2);
        }
      bf16x8 uf[4], u2f[4], thf[4];
      if (fl & 1u){
        unsigned o = *(const unsigned*)(ws + WS_OFF1 + (t * 64 + rq) * 4);
        #pragma unroll
        for (int kt = 0; kt < 4; ++kt) uf[kt] = *(const bf16x8*)(ws + WS_HEAP + o + (kt * 32 + ko) * 2);
      }
      if (fl & 2u){
        unsigned o = *(const unsigned*)(ws + WS_OFF2 + (t * 64 + rq) * 4);
        #pragma unroll
        for (int kt = 0; kt < 4; ++kt) u2f[kt] = *(const bf16x8*)(ws + WS_HEAP + o + (kt * 32 + ko) * 2);
      }
      #pragma unroll
      for (int kt = 0; kt < 4; ++kt) thf[kt] = *(const bf16x8*)(th_rd + rq * 128 + kt * 32 + ko);

      f32x4 acc[4][2];
      #pragma unroll
      for (int g = 0; g < 4; ++g)
        #pragma unroll
        for (int hn = 0; hn < 2; ++hn) acc[g][hn] = (f32x4){0.f, 0.f, 0.f, 0.f};

      #pragma unroll
      for (int g = 0; g < 4; ++g)
        #pragma unroll
        for (int hn = 0; hn < 2; ++hn){
          int nt = g * 8 + 2 * w + hn;
          #pragma unroll
          for (int kt = 0; kt < 4; ++kt){
            bf16x8 wh = *(const bf16x8*)(smem + ((nt * 4 + kt) * 64 + l) * 8);
            acc[g][hn] = __builtin_amdgcn_mfma_f32_16x16x32_bf16(thf[kt], wh, acc[g][hn], 0, 0, 0);
          }
          if (fl & 1u)
            #pragma unroll
            for (int kt = 0; kt < 4; ++kt)
              acc[g][hn] = __builtin_amdgcn_mfma_f32_16x16x32_bf16(uf[kt], ws1f[g][hn][kt], acc[g][hn], 0, 0, 0);
          if (fl & 2u)
            #pragma unroll
            for (int kt = 0; kt < 4; ++kt)
              acc[g][hn] = __builtin_amdgcn_mfma_f32_16x16x32_bf16(u2f[kt], ws2f[g][hn][kt], acc[g][hn], 0, 0, 0);
        }
      #pragma unroll
      for (int hn = 0; hn < 2; ++hn)
        #pragma unroll
        for (int j = 0; j < 4; ++j){
          int row = q * 16 + 4 * (l >> 4) + j;
          int dim = w * 32 + hn * 16 + (l & 15);
          float iv = acc[0][hn][j] + h2f(xsv[0][hn][j]);
          float fv = acc[1][hn][j] + h2f(xsv[1][hn][j]);
          float gv = acc[2][hn][j] + h2f(xsv[2][hn][j]);
          float ov = acc[3][hn][j] + h2f(xsv[3][hn][j]);
          float tc2 = sigf(fv) * tcr[q][hn][j] + sigf(iv) * tanhf_(gv);
          tcr[q][hn][j] = tc2;
          th_wr[row * 128 + dim] = f2bf(sigf(ov) * tanhf_(tc2));
        }
    }
    __syncthreads();

    // ---------- composition (reduce steps) ----------
    if (fl & 4u){
      int rord[4][4];
      unsigned o2c[4];
      #pragma unroll
      for (int mt = 0; mt < 4; ++mt){
        o2c[mt] = *(const unsigned*)(ws + WS_OFF2 + (t * 64 + mt * 16 + (l & 15)) * 4);
        #pragma unroll
        for (int j = 0; j < 4; ++j)
          rord[mt][j] = *(const int*)(ws + WS_RORD + (t * 64 + mt * 16 + 4 * (l >> 4) + j) * 4);
      }
      float tg[4][2][4], p1v[4][2][4], ccv[4][2][4];
      #pragma unroll
      for (int p5 = 0; p5 < 5; ++p5){
        f32x4 acc[4][2];
        #pragma unroll
        for (int mt = 0; mt < 4; ++mt)
          #pragma unroll
          for (int hn = 0; hn < 2; ++hn) acc[mt][hn] = (f32x4){0.f, 0.f, 0.f, 0.f};
        #pragma unroll
        for (int kt = 0; kt < 4; ++kt){
          bf16x8 wlf[2];
          #pragma unroll
          for (int hn = 0; hn < 2; ++hn)
            wlf[hn] = *(const bf16x8*)(ws + WS_WL + (((p5 * 8 + 2 * w + hn) * 4 + kt) * 64 + l) * 16);
          #pragma unroll
          for (int mt = 0; mt < 4; ++mt){
            bf16x8 u2 = *(const bf16x8*)(ws + WS_HEAP + o2c[mt] + (kt * 32 + ko) * 2);
            #pragma unroll
            for (int hn = 0; hn < 2; ++hn)
              acc[mt][hn] = __builtin_amdgcn_mfma_f32_16x16x32_bf16(u2, wlf[hn], acc[mt][hn], 0, 0, 0);
          }
        }
        #pragma unroll
        for (int kt = 0; kt < 4; ++kt){
          bf16x8 wtf[2];
          #pragma unroll
          for (int hn = 0; hn < 2; ++hn)
            wtf[hn] = *(const bf16x8*)(ws + WS_WT + (((p5 * 8 + 2 * w + hn) * 4 + kt) * 64 + l) * 16);
          #pragma unroll
          for (int mt = 0; mt < 4; ++mt){
            bf16x8 t2 = *(const bf16x8*)(th_wr + (mt * 16 + (l & 15)) * 128 + kt * 32 + ko);
            #pragma unroll
            for (int hn = 0; hn < 2; ++hn)
              acc[mt][hn] = __builtin_amdgcn_mfma_f32_16x16x32_bf16(t2, wtf[hn], acc[mt][hn], 0, 0, 0);
          }
        }
        #pragma unroll
        for (int mt = 0; mt < 4; ++mt)
          #pragma unroll
          for (int hn = 0; hn < 2; ++hn)
            #pragma unroll
            for (int j = 0; j < 4; ++j){
              int row = mt * 16 + 4 * (l >> 4) + j;
              int dim = w * 32 + hn * 16 + (l & 15);
              int col = p5 * 128 + dim;
              int od = rord[mt][j];
              int odc = od < 0 ? 0 : od;
              float pre = acc[mt][hn][j]
                        + h2f(*(const unsigned short*)(ws + WS_CS + ((size_t)(odc * 640 + col) * 64 + row) * 2));
              if (p5 == 0) tg[mt][hn][j] = tanhf_(pre);
              else if (p5 == 1) p1v[mt][hn][j] = sigf(pre) * tg[mt][hn][j];
              else if (p5 == 2){
                unsigned cf = *(const unsigned*)(ws + WS_COF2 + (t * 64 + row) * 4);
                float s2c = (cf & 0x80000000u)
                          ? *(const float*)(ws + WS_CC + (cf & 0x7fffffffu) + dim * 4)
                          : *(const float*)((const char*)buffers + cf + dim * 4);
                ccv[mt][hn][j] = sigf(pre) * s2c + p1v[mt][hn][j];
              } else if (p5 == 3){
                unsigned cf = *(const unsigned*)(ws + WS_COF1 + (t * 64 + row) * 4);
                float s1c = (cf & 0x80000000u)
                          ? *(const float*)(ws + WS_CC + (cf & 0x7fffffffu) + dim * 4)
                          : *(const float*)((const char*)buffers + cf + dim * 4);
                ccv[mt][hn][j] += sigf(pre) * s1c;
              } else {
                float h = sigf(pre) * tanhf_(ccv[mt][hn][j]);
                if (od >= 0){
                  *(unsigned short*)(ws + WS_HEAP + (size_t)(1 + od * 64 + row) * 256 + dim * 2) = f2bf(h);
                  *(float*)(ws + WS_CC + ((size_t)(od * 64 + row) * 128 + dim) * 4) = ccv[mt][hn][j];
                }
              }
            }
      }
      __syncthreads();
    }
  }

  // ---------- epilogue ----------
  __syncthreads();
  for (int i = tid; i < 8192; i += 256){
    int b = i >> 7, dim = i & 127;
    unsigned src = *(const unsigned*)(ws + WS_OSRC + b * 4);
    const unsigned short* p = (src & 0x80000000u)
        ? (const unsigned short*)(ws + WS_HEAP + (src & 0x7fffffffu) + dim * 2)
        : (const unsigned short*)(ws + WS_BUFH + src + dim * 2);
    out[i] = bf2f(*p);
  }
}

extern "C" void kernel_launch(void* const* d_in, const int* in_sizes, int n_in,
                              void* d_out, int out_size, void* d_ws, size_t ws_size,
                              hipStream_t stream){
  const float* buffers = (const float*)d_in[0];
  const int*   trans   = (const int*)d_in[1];
  const float* W_ih    = (const float*)d_in[2];
  const float* W_hh    = (const float*)d_in[3];
  const float* b_ih    = (const float*)d_in[4];
  const float* b_hh    = (const float*)d_in[5];
  const float* Wl      = (const float*)d_in[6];
  const float* bl      = (const float*)d_in[7];
  const float* Wr      = (const float*)d_in[8];
  const float* Wt      = (const float*)d_in[9];
  unsigned char* ws = (unsigned char*)d_ws;
  k0_sim  <<<dim3(1),    dim3(64),  0,      stream>>>(trans, ws);
  k1_prep <<<dim3(2048), dim3(256), 0,      stream>>>(buffers, W_ih, W_hh, Wl, Wr, Wt, ws);
  k2_xs   <<<dim3(189),  dim3(256), 0,      stream>>>(b_ih, b_hh, ws);
  k2b_cs  <<<dim3(189),  dim3(256), 0,      stream>>>(bl, ws);
  k3_serial<<<dim3(1),   dim3(256), 131072, stream>>>(buffers, (float*)d_out, ws);
}

// Round 8
// 1985.112 us; speedup vs baseline: 5.5073x; 5.5073x over previous
//
#include <hip/hip_runtime.h>

#define D 128
#define NB 64
#define LBUF 96
#define T_STEPS 189

typedef __bf16 bf16x8 __attribute__((ext_vector_type(8)));
typedef float f32x4 __attribute__((ext_vector_type(4)));
typedef unsigned short u16x4v __attribute__((ext_vector_type(4)));
typedef unsigned short u16x8v __attribute__((ext_vector_type(8)));

// ---------------- ws layout (bytes) ----------------
#define WS_HEAP   0u           // bf16 rows of 128 (256B): row0 zeros; row (1+ord*64+b) = comp h
#define WS_BUFH   1541120u     // bf16 rows: row0 zeros; row (1+br*64+b) = h-half of buffers
#define WS_CC     3115008u     // float[94*64][128] comp c results
#define WS_XS     6195200u     // f16 [189][512 col][64 row] tracker static pre-acts
#define WS_CS     18581504u    // f16 [94 ord][640 col][64 row] comp static pre-acts
#define WS_WBUF   26281984u    // bf16 frag tables (B-operand layout)
#define WS_WS1    26413056u
#define WS_WS2    26544128u
#define WS_WHH    26675200u
#define WS_WL     26806272u
#define WS_WR     26970112u
#define WS_WT     27133952u
#define WS_THWS   27297792u    // bf16 [2][64][128] tracker-h ping-pong
#define WS_OFF1   27330560u    // u32[189*64] runtime-s1 heap byte off (0 = zero row)
#define WS_OFF2   27378944u
#define WS_BOFF   27427328u    // u32[189*64] buf-top byte off into BUFH
#define WS_S1B    27475712u    // u32[189*64] static-s1 byte off into BUFH (0 = zero row)
#define WS_S2B    27524096u
#define WS_COF1   27572480u    // u32[189*64] comp s1-c source (bit31: CC vs buffers), byte off
#define WS_COF2   27620864u
#define WS_RORD   27669248u    // i32[189*64] reduce ordinal or -1
#define WS_SFLG   27717632u    // u32[189] flags: 1=rt s1, 2=rt s2, 4=reduce
#define WS_OSRC   27718400u    // u32[64] final top source

#define RTAG 0x40000000
#define TMSK 0x3fffffff

__device__ __forceinline__ unsigned short f2bf(float f){
  unsigned x = __builtin_bit_cast(unsigned, f);
  unsigned r = (x + 0x7fffu + ((x >> 16) & 1u)) >> 16;
  return (unsigned short)r;
}
__device__ __forceinline__ float bf2f(unsigned short u){
  unsigned x = ((unsigned)u) << 16;
  return __builtin_bit_cast(float, x);
}
__device__ __forceinline__ unsigned short f2h(float x){
  _Float16 h = (_Float16)x;
  return __builtin_bit_cast(unsigned short, h);
}
__device__ __forceinline__ float h2f(unsigned short u){
  return (float)__builtin_bit_cast(_Float16, u);
}
__device__ __forceinline__ float sigf(float x){ return 1.f / (1.f + __expf(-x)); }
__device__ __forceinline__ float tanhf_(float x){ return 1.f - 2.f / (__expf(2.f * x) + 1.f); }

// ============ K0: symbolic stack simulation (1 wave) ============
__global__ void k0_sim(const int* __restrict__ trans, unsigned char* __restrict__ ws){
  __shared__ int tag[64][99];
  const int b = threadIdx.x;
  unsigned* OFF1 = (unsigned*)(ws + WS_OFF1);
  unsigned* OFF2 = (unsigned*)(ws + WS_OFF2);
  unsigned* BOFF = (unsigned*)(ws + WS_BOFF);
  unsigned* S1B  = (unsigned*)(ws + WS_S1B);
  unsigned* S2B  = (unsigned*)(ws + WS_S2B);
  unsigned* COF1 = (unsigned*)(ws + WS_COF1);
  unsigned* COF2 = (unsigned*)(ws + WS_COF2);
  int*      RORD = (int*)(ws + WS_RORD);
  unsigned* SFLG = (unsigned*)(ws + WS_SFLG);
  unsigned* OSRC = (unsigned*)(ws + WS_OSRC);

  tag[b][0] = 0; tag[b][1] = 0;
  int sp = 2, bp = LBUF, rc = 0;
  for (int t = 0; t < T_STEPS; ++t){
    int tr = trans[t * 64 + b];
    int s1 = tag[b][sp - 1], s2 = tag[b][sp - 2];
    int bt = bp - 1;
    int r1 = (s1 & RTAG) != 0, r2 = (s2 & RTAG) != 0;
    int ix = t * 64 + b;
    OFF1[ix] = r1 ? (unsigned)((1 + (s1 & TMSK) * 64 + b) * 256) : 0u;
    OFF2[ix] = r2 ? (unsigned)((1 + (s2 & TMSK) * 64 + b) * 256) : 0u;
    BOFF[ix] = (unsigned)((1 + bt * 64 + b) * 256);
    S1B[ix]  = r1 ? 0u : (unsigned)((1 + s1 * 64 + b) * 256);
    S2B[ix]  = r2 ? 0u : (unsigned)((1 + s2 * 64 + b) * 256);
    int red = (tr == 2), sh = (tr == 3);
    unsigned f = (__any(r1) ? 1u : 0u) | (__any(r2) ? 2u : 0u) | (__any(red) ? 4u : 0u);
    if (b == 0) SFLG[t] = f;
    unsigned c1 = 0, c2 = 0; int ro = -1;
    if (red){
      ro = rc++;
      c1 = r1 ? (0x80000000u | (unsigned)((((s1 & TMSK) * 64 + b)) << 9))
              : (unsigned)((s1 * 64 + b) * 1024 + 512);
      c2 = r2 ? (0x80000000u | (unsigned)((((s2 & TMSK) * 64 + b)) << 9))
              : (unsigned)((s2 * 64 + b) * 1024 + 512);
      tag[b][sp - 2] = RTAG | ro;
      sp -= 1;
    } else if (sh){
      tag[b][sp] = bt; sp++; bp--;
    }
    COF1[ix] = c1; COF2[ix] = c2; RORD[ix] = ro;
  }
  int top = tag[b][sp - 1];
  OSRC[b] = (top & RTAG) ? (0x80000000u | (unsigned)((1 + (top & TMSK) * 64 + b) * 256))
                         : (unsigned)((1 + top * 64 + b) * 256);
}

// ============ K1: weight frag tables + bufh + zero rows ============
__global__ __launch_bounds__(256) void k1_prep(
    const float* __restrict__ buffers, const float* __restrict__ W_ih,
    const float* __restrict__ W_hh, const float* __restrict__ Wl,
    const float* __restrict__ Wr, const float* __restrict__ Wt,
    unsigned char* __restrict__ ws)
{
  const int gid = blockIdx.x * 256 + threadIdx.x;
  const int gsz = gridDim.x * 256;
  const int NWB = 507904;
  const int NBU = 6145 * 128;
  for (int i = gid; i < NWB + NBU + 128 + 16384; i += gsz){
    if (i < NWB){
      int e = i; const float* src; unsigned dst; int LD, KO;
      if      (e < 65536)  { src = W_ih; dst = WS_WBUF; LD = 384; KO = 0; }
      else if (e < 131072) { src = W_ih; dst = WS_WS1;  LD = 384; KO = 128; e -= 65536; }
      else if (e < 196608) { src = W_ih; dst = WS_WS2;  LD = 384; KO = 256; e -= 131072; }
      else if (e < 262144) { src = W_hh; dst = WS_WHH;  LD = 128; KO = 0;   e -= 196608; }
      else if (e < 344064) { src = Wl;   dst = WS_WL;   LD = 128; KO = 0;   e -= 262144; }
      else if (e < 425984) { src = Wr;   dst = WS_WR;   LD = 128; KO = 0;   e -= 344064; }
      else                 { src = Wt;   dst = WS_WT;   LD = 128; KO = 0;   e -= 425984; }
      int j = e & 7, l = (e >> 3) & 63, kt = (e >> 9) & 3, nt = e >> 11;
      float v = src[(nt * 16 + (l & 15)) * LD + KO + kt * 32 + (l >> 4) * 8 + j];
      *(unsigned short*)(ws + dst + (size_t)e * 2) = f2bf(v);
    } else if (i < NWB + NBU){
      int e = i - NWB; int row = e >> 7, k = e & 127;
      unsigned short v = (row == 0) ? (unsigned short)0
                                    : f2bf(buffers[(size_t)(row - 1) * 256 + k]);
      *(unsigned short*)(ws + WS_BUFH + (size_t)e * 2) = v;
    } else if (i < NWB + NBU + 128){
      int k = i - NWB - NBU;
      *(unsigned short*)(ws + WS_HEAP + k * 2) = 0;
    } else {
      int k = i - NWB - NBU - 128;
      *(unsigned short*)(ws + WS_THWS + k * 2) = 0;
    }
  }
}

// ============ K2: XS[t] static tracker pre-acts (189 WGs) ============
__global__ __launch_bounds__(256, 1) void k2_xs(
    const float* __restrict__ b_ih, const float* __restrict__ b_hh,
    unsigned char* __restrict__ ws)
{
  const int tid = threadIdx.x, l = tid & 63, w = tid >> 6, t = blockIdx.x;
  const int ko = (l >> 4) * 8;
  unsigned ob[4], o1[4], o2[4];
  #pragma unroll
  for (int mt = 0; mt < 4; ++mt){
    int r = mt * 16 + (l & 15);
    ob[mt] = *(const unsigned*)(ws + WS_BOFF + (t * 64 + r) * 4);
    o1[mt] = *(const unsigned*)(ws + WS_S1B  + (t * 64 + r) * 4);
    o2[mt] = *(const unsigned*)(ws + WS_S2B  + (t * 64 + r) * 4);
  }
  bf16x8 aB[4][4], a1[4][4], a2[4][4];
  #pragma unroll
  for (int mt = 0; mt < 4; ++mt)
    #pragma unroll
    for (int kt = 0; kt < 4; ++kt){
      aB[mt][kt] = *(const bf16x8*)(ws + WS_BUFH + ob[mt] + (kt * 32 + ko) * 2);
      a1[mt][kt] = *(const bf16x8*)(ws + WS_BUFH + o1[mt] + (kt * 32 + ko) * 2);
      a2[mt][kt] = *(const bf16x8*)(ws + WS_BUFH + o2[mt] + (kt * 32 + ko) * 2);
    }
  for (int i = 0; i < 8; ++i){
    int nt = w * 8 + i;
    f32x4 acc[4];
    #pragma unroll
    for (int mt = 0; mt < 4; ++mt) acc[mt] = (f32x4){0.f, 0.f, 0.f, 0.f};
    #pragma unroll
    for (int kt = 0; kt < 4; ++kt){
      bf16x8 bB = *(const bf16x8*)(ws + WS_WBUF + ((nt * 4 + kt) * 64 + l) * 16);
      #pragma unroll
      for (int mt = 0; mt < 4; ++mt) acc[mt] = __builtin_amdgcn_mfma_f32_16x16x32_bf16(aB[mt][kt], bB, acc[mt], 0, 0, 0);
    }
    #pragma unroll
    for (int kt = 0; kt < 4; ++kt){
      bf16x8 bB = *(const bf16x8*)(ws + WS_WS1 + ((nt * 4 + kt) * 64 + l) * 16);
      #pragma unroll
      for (int mt = 0; mt < 4; ++mt) acc[mt] = __builtin_amdgcn_mfma_f32_16x16x32_bf16(a1[mt][kt], bB, acc[mt], 0, 0, 0);
    }
    #pragma unroll
    for (int kt = 0; kt < 4; ++kt){
      bf16x8 bB = *(const bf16x8*)(ws + WS_WS2 + ((nt * 4 + kt) * 64 + l) * 16);
      #pragma unroll
      for (int mt = 0; mt < 4; ++mt) acc[mt] = __builtin_amdgcn_mfma_f32_16x16x32_bf16(a2[mt][kt], bB, acc[mt], 0, 0, 0);
    }
    int col = nt * 16 + (l & 15);
    float bv = b_ih[col] + b_hh[col];
    #pragma unroll
    for (int mt = 0; mt < 4; ++mt){
      u16x4v pk;
      #pragma unroll
      for (int j = 0; j < 4; ++j) pk[j] = f2h(acc[mt][j] + bv);
      *(u16x4v*)(ws + WS_XS + ((size_t)((t * 512 + col) * 64) + 16 * mt + 4 * (l >> 4)) * 2) = pk;
    }
  }
}

// ============ K2b: CS[ord] static comp pre-acts (189 WGs) ============
__global__ __launch_bounds__(256, 1) void k2b_cs(
    const float* __restrict__ bl, unsigned char* __restrict__ ws)
{
  const int t = blockIdx.x;
  unsigned fl = *(const unsigned*)(ws + WS_SFLG + t * 4);
  if (!(fl & 4u)) return;
  const int tid = threadIdx.x, l = tid & 63, w = tid >> 6;
  const int ko = (l >> 4) * 8;
  unsigned o1[4], o2[4];
  int rord[4][4];
  #pragma unroll
  for (int mt = 0; mt < 4; ++mt){
    int r = mt * 16 + (l & 15);
    o1[mt] = *(const unsigned*)(ws + WS_S1B + (t * 64 + r) * 4);
    o2[mt] = *(const unsigned*)(ws + WS_S2B + (t * 64 + r) * 4);
    #pragma unroll
    for (int j = 0; j < 4; ++j)
      rord[mt][j] = *(const int*)(ws + WS_RORD + (t * 64 + mt * 16 + 4 * (l >> 4) + j) * 4);
  }
  bf16x8 a1[4][4], a2[4][4];
  #pragma unroll
  for (int mt = 0; mt < 4; ++mt)
    #pragma unroll
    for (int kt = 0; kt < 4; ++kt){
      a1[mt][kt] = *(const bf16x8*)(ws + WS_BUFH + o1[mt] + (kt * 32 + ko) * 2);
      a2[mt][kt] = *(const bf16x8*)(ws + WS_BUFH + o2[mt] + (kt * 32 + ko) * 2);
    }
  for (int i = 0; i < 10; ++i){
    int nt = w * 10 + i;
    f32x4 acc[4];
    #pragma unroll
    for (int mt = 0; mt < 4; ++mt) acc[mt] = (f32x4){0.f, 0.f, 0.f, 0.f};
    #pragma unroll
    for (int kt = 0; kt < 4; ++kt){
      bf16x8 bR = *(const bf16x8*)(ws + WS_WR + ((nt * 4 + kt) * 64 + l) * 16);
      #pragma unroll
      for (int mt = 0; mt < 4; ++mt) acc[mt] = __builtin_amdgcn_mfma_f32_16x16x32_bf16(a1[mt][kt], bR, acc[mt], 0, 0, 0);
    }
    #pragma unroll
    for (int kt = 0; kt < 4; ++kt){
      bf16x8 bL = *(const bf16x8*)(ws + WS_WL + ((nt * 4 + kt) * 64 + l) * 16);
      #pragma unroll
      for (int mt = 0; mt < 4; ++mt) acc[mt] = __builtin_amdgcn_mfma_f32_16x16x32_bf16(a2[mt][kt], bL, acc[mt], 0, 0, 0);
    }
    int col = nt * 16 + (l & 15);
    float bv = bl[col];
    #pragma unroll
    for (int mt = 0; mt < 4; ++mt)
      #pragma unroll
      for (int j = 0; j < 4; ++j){
        int od = rord[mt][j];
        if (od >= 0){
          int row = mt * 16 + 4 * (l >> 4) + j;
          *(unsigned short*)(ws + WS_CS + ((size_t)(od * 640 + col) * 64 + row) * 2) = f2h(acc[mt][j] + bv);
        }
      }
  }
}

// ============ K3: serial chain — 4 independent WGs x 16 rows, 8 waves ============
__global__ __launch_bounds__(512, 1) void k3_serial(
    const float* __restrict__ buffers, float* __restrict__ out,
    unsigned char* __restrict__ ws)
{
  extern __shared__ unsigned short smem[];   // 131072 B: W_hh frag table
  const int tid = threadIdx.x, l = tid & 63, w = tid >> 6;   // wave 0..7
  const int g = blockIdx.x;                  // rows 16g..16g+15 (independent!)
  const int rb = 16 * g;
  const int r16 = l & 15;
  const int hi = l >> 4;
  const int koff = hi * 8;
  const int dim = 16 * w + r16;              // owned dim slice

  // stage W_hh frags into LDS
  {
    const u16x8v* src = (const u16x8v*)(ws + WS_WHH);
    u16x8v* dst = (u16x8v*)smem;
    for (int i = tid; i < 8192; i += 512) dst[i] = src[i];
  }
  // resident W_s1 / W_s2 frags: nt = 8q + w  (128 VGPR total)
  bf16x8 ws1f[4][4], ws2f[4][4];
  #pragma unroll
  for (int q = 0; q < 4; ++q)
    #pragma unroll
    for (int kt = 0; kt < 4; ++kt){
      int nt = 8 * q + w;
      ws1f[q][kt] = *(const bf16x8*)(ws + WS_WS1 + ((nt * 4 + kt) * 64 + l) * 16);
      ws2f[q][kt] = *(const bf16x8*)(ws + WS_WS2 + ((nt * 4 + kt) * 64 + l) * 16);
    }
  float tcr[4] = {0.f, 0.f, 0.f, 0.f};       // tc state: rows rb+4*hi+j, dim
  __syncthreads();

  for (int t = 0; t < T_STEPS; ++t){
    const unsigned fl = __builtin_amdgcn_readfirstlane(*(const unsigned*)(ws + WS_SFLG + t * 4));
    unsigned short* th_rd = (unsigned short*)(ws + WS_THWS + (t & 1) * 16384);
    unsigned short* th_wr = (unsigned short*)(ws + WS_THWS + ((t + 1) & 1) * 16384);

    unsigned o1 = *(const unsigned*)(ws + WS_OFF1 + (t * 64 + rb + r16) * 4);
    unsigned o2 = *(const unsigned*)(ws + WS_OFF2 + (t * 64 + rb + r16) * 4);

    // ---------- tracker ----------
    bf16x8 thf[4];
    #pragma unroll
    for (int kt = 0; kt < 4; ++kt)
      thf[kt] = *(const bf16x8*)(th_rd + (rb + r16) * 128 + kt * 32 + koff);

    f32x4 acc[4];
    #pragma unroll
    for (int q = 0; q < 4; ++q) acc[q] = (f32x4){0.f, 0.f, 0.f, 0.f};

    #pragma unroll
    for (int q = 0; q < 4; ++q)
      #pragma unroll
      for (int kt = 0; kt < 4; ++kt){
        bf16x8 wh = *(const bf16x8*)(smem + (((8 * q + w) * 4 + kt) * 64 + l) * 8);
        acc[q] = __builtin_amdgcn_mfma_f32_16x16x32_bf16(thf[kt], wh, acc[q], 0, 0, 0);
      }
    if (fl & 1u){
      bf16x8 rf[4];
      #pragma unroll
      for (int kt = 0; kt < 4; ++kt)
        rf[kt] = *(const bf16x8*)(ws + WS_HEAP + o1 + (kt * 32 + koff) * 2);
      #pragma unroll
      for (int q = 0; q < 4; ++q)
        #pragma unroll
        for (int kt = 0; kt < 4; ++kt)
          acc[q] = __builtin_amdgcn_mfma_f32_16x16x32_bf16(rf[kt], ws1f[q][kt], acc[q], 0, 0, 0);
    }
    if (fl & 2u){
      bf16x8 rf[4];
      #pragma unroll
      for (int kt = 0; kt < 4; ++kt)
        rf[kt] = *(const bf16x8*)(ws + WS_HEAP + o2 + (kt * 32 + koff) * 2);
      #pragma unroll
      for (int q = 0; q < 4; ++q)
        #pragma unroll
        for (int kt = 0; kt < 4; ++kt)
          acc[q] = __builtin_amdgcn_mfma_f32_16x16x32_bf16(rf[kt], ws2f[q][kt], acc[q], 0, 0, 0);
    }
    // XS + elementwise (all lane-local: acc row = rb+4*hi+j, col = q*128+dim)
    u16x4v xsq[4];
    #pragma unroll
    for (int q = 0; q < 4; ++q)
      xsq[q] = *(const u16x4v*)(ws + WS_XS + ((size_t)((t * 512 + q * 128 + dim)) * 64 + rb + 4 * hi) * 2);
    #pragma unroll
    for (int j = 0; j < 4; ++j){
      float iv = acc[0][j] + h2f(xsq[0][j]);
      float fv = acc[1][j] + h2f(xsq[1][j]);
      float gv = acc[2][j] + h2f(xsq[2][j]);
      float ov = acc[3][j] + h2f(xsq[3][j]);
      float tc2 = sigf(fv) * tcr[j] + sigf(iv) * tanhf_(gv);
      tcr[j] = tc2;
      th_wr[(rb + 4 * hi + j) * 128 + dim] = f2bf(sigf(ov) * tanhf_(tc2));
    }
    __syncthreads();

    // ---------- composition (reduce steps) ----------
    if (fl & 4u){
      const int od0 = __builtin_amdgcn_readfirstlane(*(const int*)(ws + WS_RORD + (t * 64 + rb) * 4));
      bf16x8 t2f[4], rcf[4];
      #pragma unroll
      for (int kt = 0; kt < 4; ++kt){
        t2f[kt] = *(const bf16x8*)(th_wr + (rb + r16) * 128 + kt * 32 + koff);
        rcf[kt] = *(const bf16x8*)(ws + WS_HEAP + o2 + (kt * 32 + koff) * 2);
      }
      f32x4 ac2[5];
      #pragma unroll
      for (int p = 0; p < 5; ++p) ac2[p] = (f32x4){0.f, 0.f, 0.f, 0.f};
      #pragma unroll
      for (int p = 0; p < 5; ++p)
        #pragma unroll
        for (int kt = 0; kt < 4; ++kt){
          bf16x8 wlf = *(const bf16x8*)(ws + WS_WL + (((8 * p + w) * 4 + kt) * 64 + l) * 16);
          bf16x8 wtf = *(const bf16x8*)(ws + WS_WT + (((8 * p + w) * 4 + kt) * 64 + l) * 16);
          ac2[p] = __builtin_amdgcn_mfma_f32_16x16x32_bf16(rcf[kt], wlf, ac2[p], 0, 0, 0);
          ac2[p] = __builtin_amdgcn_mfma_f32_16x16x32_bf16(t2f[kt], wtf, ac2[p], 0, 0, 0);
        }
      u16x4v csq[5];
      #pragma unroll
      for (int p = 0; p < 5; ++p)
        csq[p] = *(const u16x4v*)(ws + WS_CS + ((size_t)(od0 * 640 + p * 128 + dim) * 64 + rb + 4 * hi) * 2);
      #pragma unroll
      for (int j = 0; j < 4; ++j){
        int row_g = rb + 4 * hi + j;
        float gv  = ac2[0][j] + h2f(csq[0][j]);
        float iv  = ac2[1][j] + h2f(csq[1][j]);
        float f1v = ac2[2][j] + h2f(csq[2][j]);
        float f2v = ac2[3][j] + h2f(csq[3][j]);
        float ov  = ac2[4][j] + h2f(csq[4][j]);
        unsigned cf2 = *(const unsigned*)(ws + WS_COF2 + (t * 64 + row_g) * 4);
        float s2c = (cf2 & 0x80000000u)
                  ? *(const float*)(ws + WS_CC + (cf2 & 0x7fffffffu) + dim * 4)
                  : *(const float*)((const char*)buffers + cf2 + dim * 4);
        unsigned cf1 = *(const unsigned*)(ws + WS_COF1 + (t * 64 + row_g) * 4);
        float s1c = (cf1 & 0x80000000u)
                  ? *(const float*)(ws + WS_CC + (cf1 & 0x7fffffffu) + dim * 4)
                  : *(const float*)((const char*)buffers + cf1 + dim * 4);
        float cc = sigf(f1v) * s2c + sigf(f2v) * s1c + sigf(iv) * tanhf_(gv);
        float hh = sigf(ov) * tanhf_(cc);
        if (od0 >= 0){
          *(unsigned short*)(ws + WS_HEAP + (size_t)(1 + od0 * 64 + row_g) * 256 + dim * 2) = f2bf(hh);
          *(float*)(ws + WS_CC + ((size_t)(od0 * 64 + row_g) * 128 + dim) * 4) = cc;
        }
      }
      __syncthreads();
    }
  }

  // ---------- epilogue (own 16 rows) ----------
  for (int i = tid; i < 16 * 128; i += 512){
    int brow = rb + (i >> 7), dm = i & 127;
    unsigned src = *(const unsigned*)(ws + WS_OSRC + brow * 4);
    const unsigned short* p = (src & 0x80000000u)
        ? (const unsigned short*)(ws + WS_HEAP + (src & 0x7fffffffu) + dm * 2)
        : (const unsigned short*)(ws + WS_BUFH + src + dm * 2);
    out[brow * 128 + dm] = bf2f(*p);
  }
}

extern "C" void kernel_launch(void* const* d_in, const int* in_sizes, int n_in,
                              void* d_out, int out_size, void* d_ws, size_t ws_size,
                              hipStream_t stream){
  const float* buffers = (const float*)d_in[0];
  const int*   trans   = (const int*)d_in[1];
  const float* W_ih    = (const float*)d_in[2];
  const float* W_hh    = (const float*)d_in[3];
  const float* b_ih    = (const float*)d_in[4];
  const float* b_hh    = (const float*)d_in[5];
  const float* Wl      = (const float*)d_in[6];
  const float* bl      = (const float*)d_in[7];
  const float* Wr      = (const float*)d_in[8];
  const float* Wt      = (const float*)d_in[9];
  unsigned char* ws = (unsigned char*)d_ws;
  k0_sim   <<<dim3(1),    dim3(64),  0,      stream>>>(trans, ws);
  k1_prep  <<<dim3(2048), dim3(256), 0,      stream>>>(buffers, W_ih, W_hh, Wl, Wr, Wt, ws);
  k2_xs    <<<dim3(189),  dim3(256), 0,      stream>>>(b_ih, b_hh, ws);
  k2b_cs   <<<dim3(189),  dim3(256), 0,      stream>>>(bl, ws);
  k3_serial<<<dim3(4),    dim3(512), 131072, stream>>>(buffers, (float*)d_out, ws);
}

// Round 9
// 1942.132 us; speedup vs baseline: 5.6292x; 1.0221x over previous
//
#include <hip/hip_runtime.h>

#define D 128
#define NB 64
#define LBUF 96
#define T_STEPS 189

typedef __bf16 bf16x8 __attribute__((ext_vector_type(8)));
typedef float f32x4 __attribute__((ext_vector_type(4)));
typedef unsigned short u16x4v __attribute__((ext_vector_type(4)));
typedef unsigned short u16x8v __attribute__((ext_vector_type(8)));

// ---------------- ws layout (bytes) ----------------
#define WS_HEAP   0u           // bf16 rows of 128 (256B): row0 zeros; row (1+ord*64+b) = comp h
#define WS_BUFH   1541120u     // bf16 rows: row0 zeros; row (1+br*64+b) = h-half of buffers
#define WS_CC     3115008u     // float[94*64][128] comp c results
#define WS_XS     6195200u     // f16 [189][4 mt][512 col][16 row]  (WG-contiguous)
#define WS_CS     18581504u    // f16 [94 ord][4 mt][640 col][16 row]
#define WS_WBUF   26281984u    // bf16 frag tables (B-operand layout)
#define WS_WS1    26413056u
#define WS_WS2    26544128u
#define WS_WHH    26675200u
#define WS_WL     26806272u
#define WS_WR     26970112u
#define WS_WT     27133952u
#define WS_THWS   27297792u    // bf16 [2][64][128] tracker-h ping-pong
#define WS_OFF1   27330560u    // u32[189*64] runtime-s1 heap byte off (0 = zero row)
#define WS_OFF2   27378944u
#define WS_BOFF   27427328u    // u32[189*64] buf-top byte off into BUFH
#define WS_S1B    27475712u    // u32[189*64] static-s1 byte off into BUFH (0 = zero row)
#define WS_S2B    27524096u
#define WS_COF1   27572480u    // u32[189*64] comp s1-c source (bit31: CC vs buffers), byte off
#define WS_COF2   27620864u
#define WS_RORD   27669248u    // i32[189*64] reduce ordinal or -1
#define WS_SFLG   27717632u    // u32[189] flags: 1=rt s1, 2=rt s2, 4=reduce
#define WS_OSRC   27718400u    // u32[64] final top source

#define RTAG 0x40000000
#define TMSK 0x3fffffff

__device__ __forceinline__ unsigned short f2bf(float f){
  unsigned x = __builtin_bit_cast(unsigned, f);
  unsigned r = (x + 0x7fffu + ((x >> 16) & 1u)) >> 16;
  return (unsigned short)r;
}
__device__ __forceinline__ float bf2f(unsigned short u){
  unsigned x = ((unsigned)u) << 16;
  return __builtin_bit_cast(float, x);
}
__device__ __forceinline__ unsigned short f2h(float x){
  _Float16 h = (_Float16)x;
  return __builtin_bit_cast(unsigned short, h);
}
__device__ __forceinline__ float h2f(unsigned short u){
  return (float)__builtin_bit_cast(_Float16, u);
}
__device__ __forceinline__ float sigf(float x){ return 1.f / (1.f + __expf(-x)); }
__device__ __forceinline__ float tanhf_(float x){ return 1.f - 2.f / (__expf(2.f * x) + 1.f); }

// ============ K0: symbolic stack simulation (1 wave) ============
__global__ void k0_sim(const int* __restrict__ trans, unsigned char* __restrict__ ws){
  __shared__ int tag[64][99];
  const int b = threadIdx.x;
  unsigned* OFF1 = (unsigned*)(ws + WS_OFF1);
  unsigned* OFF2 = (unsigned*)(ws + WS_OFF2);
  unsigned* BOFF = (unsigned*)(ws + WS_BOFF);
  unsigned* S1B  = (unsigned*)(ws + WS_S1B);
  unsigned* S2B  = (unsigned*)(ws + WS_S2B);
  unsigned* COF1 = (unsigned*)(ws + WS_COF1);
  unsigned* COF2 = (unsigned*)(ws + WS_COF2);
  int*      RORD = (int*)(ws + WS_RORD);
  unsigned* SFLG = (unsigned*)(ws + WS_SFLG);
  unsigned* OSRC = (unsigned*)(ws + WS_OSRC);

  tag[b][0] = 0; tag[b][1] = 0;
  int sp = 2, bp = LBUF, rc = 0;
  for (int t = 0; t < T_STEPS; ++t){
    int tr = trans[t * 64 + b];
    int s1 = tag[b][sp - 1], s2 = tag[b][sp - 2];
    int bt = bp - 1;
    int r1 = (s1 & RTAG) != 0, r2 = (s2 & RTAG) != 0;
    int ix = t * 64 + b;
    OFF1[ix] = r1 ? (unsigned)((1 + (s1 & TMSK) * 64 + b) * 256) : 0u;
    OFF2[ix] = r2 ? (unsigned)((1 + (s2 & TMSK) * 64 + b) * 256) : 0u;
    BOFF[ix] = (unsigned)((1 + bt * 64 + b) * 256);
    S1B[ix]  = r1 ? 0u : (unsigned)((1 + s1 * 64 + b) * 256);
    S2B[ix]  = r2 ? 0u : (unsigned)((1 + s2 * 64 + b) * 256);
    int red = (tr == 2), sh = (tr == 3);
    unsigned f = (__any(r1) ? 1u : 0u) | (__any(r2) ? 2u : 0u) | (__any(red) ? 4u : 0u);
    if (b == 0) SFLG[t] = f;
    unsigned c1 = 0, c2 = 0; int ro = -1;
    if (red){
      ro = rc++;
      c1 = r1 ? (0x80000000u | (unsigned)((((s1 & TMSK) * 64 + b)) << 9))
              : (unsigned)((s1 * 64 + b) * 1024 + 512);
      c2 = r2 ? (0x80000000u | (unsigned)((((s2 & TMSK) * 64 + b)) << 9))
              : (unsigned)((s2 * 64 + b) * 1024 + 512);
      tag[b][sp - 2] = RTAG | ro;
      sp -= 1;
    } else if (sh){
      tag[b][sp] = bt; sp++; bp--;
    }
    COF1[ix] = c1; COF2[ix] = c2; RORD[ix] = ro;
  }
  int top = tag[b][sp - 1];
  OSRC[b] = (top & RTAG) ? (0x80000000u | (unsigned)((1 + (top & TMSK) * 64 + b) * 256))
                         : (unsigned)((1 + top * 64 + b) * 256);
}

// ============ K1: weight frag tables + bufh + zero rows ============
__global__ __launch_bounds__(256) void k1_prep(
    const float* __restrict__ buffers, const float* __restrict__ W_ih,
    const float* __restrict__ W_hh, const float* __restrict__ Wl,
    const float* __restrict__ Wr, const float* __restrict__ Wt,
    unsigned char* __restrict__ ws)
{
  const int gid = blockIdx.x * 256 + threadIdx.x;
  const int gsz = gridDim.x * 256;
  const int NWB = 507904;
  const int NBU = 6145 * 128;
  for (int i = gid; i < NWB + NBU + 128 + 16384; i += gsz){
    if (i < NWB){
      int e = i; const float* src; unsigned dst; int LD, KO;
      if      (e < 65536)  { src = W_ih; dst = WS_WBUF; LD = 384; KO = 0; }
      else if (e < 131072) { src = W_ih; dst = WS_WS1;  LD = 384; KO = 128; e -= 65536; }
      else if (e < 196608) { src = W_ih; dst = WS_WS2;  LD = 384; KO = 256; e -= 131072; }
      else if (e < 262144) { src = W_hh; dst = WS_WHH;  LD = 128; KO = 0;   e -= 196608; }
      else if (e < 344064) { src = Wl;   dst = WS_WL;   LD = 128; KO = 0;   e -= 262144; }
      else if (e < 425984) { src = Wr;   dst = WS_WR;   LD = 128; KO = 0;   e -= 344064; }
      else                 { src = Wt;   dst = WS_WT;   LD = 128; KO = 0;   e -= 425984; }
      int j = e & 7, l = (e >> 3) & 63, kt = (e >> 9) & 3, nt = e >> 11;
      float v = src[(nt * 16 + (l & 15)) * LD + KO + kt * 32 + (l >> 4) * 8 + j];
      *(unsigned short*)(ws + dst + (size_t)e * 2) = f2bf(v);
    } else if (i < NWB + NBU){
      int e = i - NWB; int row = e >> 7, k = e & 127;
      unsigned short v = (row == 0) ? (unsigned short)0
                                    : f2bf(buffers[(size_t)(row - 1) * 256 + k]);
      *(unsigned short*)(ws + WS_BUFH + (size_t)e * 2) = v;
    } else if (i < NWB + NBU + 128){
      int k = i - NWB - NBU;
      *(unsigned short*)(ws + WS_HEAP + k * 2) = 0;
    } else {
      int k = i - NWB - NBU - 128;
      *(unsigned short*)(ws + WS_THWS + k * 2) = 0;
    }
  }
}

// ============ K2: XS[t] static tracker pre-acts (189 WGs) ============
__global__ __launch_bounds__(256, 1) void k2_xs(
    const float* __restrict__ b_ih, const float* __restrict__ b_hh,
    unsigned char* __restrict__ ws)
{
  const int tid = threadIdx.x, l = tid & 63, w = tid >> 6, t = blockIdx.x;
  const int ko = (l >> 4) * 8;
  unsigned ob[4], o1[4], o2[4];
  #pragma unroll
  for (int mt = 0; mt < 4; ++mt){
    int r = mt * 16 + (l & 15);
    ob[mt] = *(const unsigned*)(ws + WS_BOFF + (t * 64 + r) * 4);
    o1[mt] = *(const unsigned*)(ws + WS_S1B  + (t * 64 + r) * 4);
    o2[mt] = *(const unsigned*)(ws + WS_S2B  + (t * 64 + r) * 4);
  }
  bf16x8 aB[4][4], a1[4][4], a2[4][4];
  #pragma unroll
  for (int mt = 0; mt < 4; ++mt)
    #pragma unroll
    for (int kt = 0; kt < 4; ++kt){
      aB[mt][kt] = *(const bf16x8*)(ws + WS_BUFH + ob[mt] + (kt * 32 + ko) * 2);
      a1[mt][kt] = *(const bf16x8*)(ws + WS_BUFH + o1[mt] + (kt * 32 + ko) * 2);
      a2[mt][kt] = *(const bf16x8*)(ws + WS_BUFH + o2[mt] + (kt * 32 + ko) * 2);
    }
  for (int i = 0; i < 8; ++i){
    int nt = w * 8 + i;
    f32x4 acc[4];
    #pragma unroll
    for (int mt = 0; mt < 4; ++mt) acc[mt] = (f32x4){0.f, 0.f, 0.f, 0.f};
    #pragma unroll
    for (int kt = 0; kt < 4; ++kt){
      bf16x8 bB = *(const bf16x8*)(ws + WS_WBUF + ((nt * 4 + kt) * 64 + l) * 16);
      #pragma unroll
      for (int mt = 0; mt < 4; ++mt) acc[mt] = __builtin_amdgcn_mfma_f32_16x16x32_bf16(aB[mt][kt], bB, acc[mt], 0, 0, 0);
    }
    #pragma unroll
    for (int kt = 0; kt < 4; ++kt){
      bf16x8 bB = *(const bf16x8*)(ws + WS_WS1 + ((nt * 4 + kt) * 64 + l) * 16);
      #pragma unroll
      for (int mt = 0; mt < 4; ++mt) acc[mt] = __builtin_amdgcn_mfma_f32_16x16x32_bf16(a1[mt][kt], bB, acc[mt], 0, 0, 0);
    }
    #pragma unroll
    for (int kt = 0; kt < 4; ++kt){
      bf16x8 bB = *(const bf16x8*)(ws + WS_WS2 + ((nt * 4 + kt) * 64 + l) * 16);
      #pragma unroll
      for (int mt = 0; mt < 4; ++mt) acc[mt] = __builtin_amdgcn_mfma_f32_16x16x32_bf16(a2[mt][kt], bB, acc[mt], 0, 0, 0);
    }
    int col = nt * 16 + (l & 15);
    float bv = b_ih[col] + b_hh[col];
    #pragma unroll
    for (int mt = 0; mt < 4; ++mt){
      u16x4v pk;
      #pragma unroll
      for (int j = 0; j < 4; ++j) pk[j] = f2h(acc[mt][j] + bv);
      // layout: [t][mt][col(512)][row16]
      *(u16x4v*)(ws + WS_XS + (((size_t)(t * 4 + mt) * 512 + col) * 16 + 4 * (l >> 4)) * 2) = pk;
    }
  }
}

// ============ K2b: CS[ord] static comp pre-acts (189 WGs) ============
__global__ __launch_bounds__(256, 1) void k2b_cs(
    const float* __restrict__ bl, unsigned char* __restrict__ ws)
{
  const int t = blockIdx.x;
  unsigned fl = *(const unsigned*)(ws + WS_SFLG + t * 4);
  if (!(fl & 4u)) return;
  const int tid = threadIdx.x, l = tid & 63, w = tid >> 6;
  const int ko = (l >> 4) * 8;
  unsigned o1[4], o2[4];
  int rord[4][4];
  #pragma unroll
  for (int mt = 0; mt < 4; ++mt){
    int r = mt * 16 + (l & 15);
    o1[mt] = *(const unsigned*)(ws + WS_S1B + (t * 64 + r) * 4);
    o2[mt] = *(const unsigned*)(ws + WS_S2B + (t * 64 + r) * 4);
    #pragma unroll
    for (int j = 0; j < 4; ++j)
      rord[mt][j] = *(const int*)(ws + WS_RORD + (t * 64 + mt * 16 + 4 * (l >> 4) + j) * 4);
  }
  bf16x8 a1[4][4], a2[4][4];
  #pragma unroll
  for (int mt = 0; mt < 4; ++mt)
    #pragma unroll
    for (int kt = 0; kt < 4; ++kt){
      a1[mt][kt] = *(const bf16x8*)(ws + WS_BUFH + o1[mt] + (kt * 32 + ko) * 2);
      a2[mt][kt] = *(const bf16x8*)(ws + WS_BUFH + o2[mt] + (kt * 32 + ko) * 2);
    }
  for (int i = 0; i < 10; ++i){
    int nt = w * 10 + i;
    f32x4 acc[4];
    #pragma unroll
    for (int mt = 0; mt < 4; ++mt) acc[mt] = (f32x4){0.f, 0.f, 0.f, 0.f};
    #pragma unroll
    for (int kt = 0; kt < 4; ++kt){
      bf16x8 bR = *(const bf16x8*)(ws + WS_WR + ((nt * 4 + kt) * 64 + l) * 16);
      #pragma unroll
      for (int mt = 0; mt < 4; ++mt) acc[mt] = __builtin_amdgcn_mfma_f32_16x16x32_bf16(a1[mt][kt], bR, acc[mt], 0, 0, 0);
    }
    #pragma unroll
    for (int kt = 0; kt < 4; ++kt){
      bf16x8 bL = *(const bf16x8*)(ws + WS_WL + ((nt * 4 + kt) * 64 + l) * 16);
      #pragma unroll
      for (int mt = 0; mt < 4; ++mt) acc[mt] = __builtin_amdgcn_mfma_f32_16x16x32_bf16(a2[mt][kt], bL, acc[mt], 0, 0, 0);
    }
    int col = nt * 16 + (l & 15);
    float bv = bl[col];
    #pragma unroll
    for (int mt = 0; mt < 4; ++mt)
      #pragma unroll
      for (int j = 0; j < 4; ++j){
        int od = rord[mt][j];
        if (od >= 0){
          // layout: [ord][mt][col(640)][row16]
          *(unsigned short*)(ws + WS_CS + (((size_t)(od * 4 + mt) * 640 + col) * 16 + 4 * (l >> 4) + j) * 2)
              = f2h(acc[mt][j] + bv);
        }
      }
  }
}

// ============ K3: serial chain — 4 independent WGs x 16 rows, 8 waves ============
__global__ __launch_bounds__(512, 1) void k3_serial(
    const float* __restrict__ buffers, float* __restrict__ out,
    unsigned char* __restrict__ ws)
{
  extern __shared__ unsigned short smem[];   // 131072 B: W_hh frag table
  const int tid = threadIdx.x, l = tid & 63, w = tid >> 6;   // wave 0..7
  const int g = blockIdx.x;                  // rows 16g..16g+15 (independent!)
  const int rb = 16 * g;
  const int r16 = l & 15;
  const int hi = l >> 4;
  const int koff = hi * 8;
  const int dim = 16 * w + r16;              // owned dim slice

  // stage W_hh frags into LDS
  {
    const u16x8v* src = (const u16x8v*)(ws + WS_WHH);
    u16x8v* dst = (u16x8v*)smem;
    for (int i = tid; i < 8192; i += 512) dst[i] = src[i];
  }
  // resident W_s1 / W_s2 frags: nt = 8q + w  (128 VGPR total)
  bf16x8 ws1f[4][4], ws2f[4][4];
  #pragma unroll
  for (int q = 0; q < 4; ++q)
    #pragma unroll
    for (int kt = 0; kt < 4; ++kt){
      int nt = 8 * q + w;
      ws1f[q][kt] = *(const bf16x8*)(ws + WS_WS1 + ((nt * 4 + kt) * 64 + l) * 16);
      ws2f[q][kt] = *(const bf16x8*)(ws + WS_WS2 + ((nt * 4 + kt) * 64 + l) * 16);
    }
  float tcr[4] = {0.f, 0.f, 0.f, 0.f};       // tc state: rows rb+4*hi+j, dim
  __syncthreads();

  for (int t = 0; t < T_STEPS; ++t){
    const unsigned fl = __builtin_amdgcn_readfirstlane(*(const unsigned*)(ws + WS_SFLG + t * 4));
    unsigned short* th_rd = (unsigned short*)(ws + WS_THWS + (t & 1) * 16384);
    unsigned short* th_wr = (unsigned short*)(ws + WS_THWS + ((t + 1) & 1) * 16384);

    unsigned o1 = *(const unsigned*)(ws + WS_OFF1 + (t * 64 + rb + r16) * 4);
    unsigned o2 = *(const unsigned*)(ws + WS_OFF2 + (t * 64 + rb + r16) * 4);

    // ---------- tracker: issue ALL independent loads up front ----------
    u16x4v xsq[4];
    #pragma unroll
    for (int q = 0; q < 4; ++q)
      xsq[q] = *(const u16x4v*)(ws + WS_XS + (((size_t)(t * 4 + g) * 512 + q * 128 + dim) * 16 + 4 * hi) * 2);
    bf16x8 thf[4];
    #pragma unroll
    for (int kt = 0; kt < 4; ++kt)
      thf[kt] = *(const bf16x8*)(th_rd + (rb + r16) * 128 + kt * 32 + koff);
    bf16x8 rf1[4], rf2[4];
    if (fl & 1u){
      #pragma unroll
      for (int kt = 0; kt < 4; ++kt)
        rf1[kt] = *(const bf16x8*)(ws + WS_HEAP + o1 + (kt * 32 + koff) * 2);
    }
    if (fl & 2u){
      #pragma unroll
      for (int kt = 0; kt < 4; ++kt)
        rf2[kt] = *(const bf16x8*)(ws + WS_HEAP + o2 + (kt * 32 + koff) * 2);
    }

    f32x4 acc[4];
    #pragma unroll
    for (int q = 0; q < 4; ++q) acc[q] = (f32x4){0.f, 0.f, 0.f, 0.f};
    #pragma unroll
    for (int q = 0; q < 4; ++q)
      #pragma unroll
      for (int kt = 0; kt < 4; ++kt){
        bf16x8 wh = *(const bf16x8*)(smem + (((8 * q + w) * 4 + kt) * 64 + l) * 8);
        acc[q] = __builtin_amdgcn_mfma_f32_16x16x32_bf16(thf[kt], wh, acc[q], 0, 0, 0);
      }
    if (fl & 1u){
      #pragma unroll
      for (int q = 0; q < 4; ++q)
        #pragma unroll
        for (int kt = 0; kt < 4; ++kt)
          acc[q] = __builtin_amdgcn_mfma_f32_16x16x32_bf16(rf1[kt], ws1f[q][kt], acc[q], 0, 0, 0);
    }
    if (fl & 2u){
      #pragma unroll
      for (int q = 0; q < 4; ++q)
        #pragma unroll
        for (int kt = 0; kt < 4; ++kt)
          acc[q] = __builtin_amdgcn_mfma_f32_16x16x32_bf16(rf2[kt], ws2f[q][kt], acc[q], 0, 0, 0);
    }
    #pragma unroll
    for (int j = 0; j < 4; ++j){
      float iv = acc[0][j] + h2f(xsq[0][j]);
      float fv = acc[1][j] + h2f(xsq[1][j]);
      float gv = acc[2][j] + h2f(xsq[2][j]);
      float ov = acc[3][j] + h2f(xsq[3][j]);
      float tc2 = sigf(fv) * tcr[j] + sigf(iv) * tanhf_(gv);
      tcr[j] = tc2;
      th_wr[(rb + 4 * hi + j) * 128 + dim] = f2bf(sigf(ov) * tanhf_(tc2));
    }
    __syncthreads();

    // ---------- composition (reduce steps) ----------
    if (fl & 4u){
      const int od0 = __builtin_amdgcn_readfirstlane(*(const int*)(ws + WS_RORD + (t * 64 + rb) * 4));
      // issue all independent loads first (CS, COF->c-source chains, th2, HEAP s2)
      u16x4v csq[5];
      #pragma unroll
      for (int p = 0; p < 5; ++p)
        csq[p] = *(const u16x4v*)(ws + WS_CS + (((size_t)(od0 * 4 + g) * 640 + p * 128 + dim) * 16 + 4 * hi) * 2);
      float s2c[4], s1c[4];
      #pragma unroll
      for (int j = 0; j < 4; ++j){
        int row_g = rb + 4 * hi + j;
        unsigned cf2 = *(const unsigned*)(ws + WS_COF2 + (t * 64 + row_g) * 4);
        unsigned cf1 = *(const unsigned*)(ws + WS_COF1 + (t * 64 + row_g) * 4);
        s2c[j] = (cf2 & 0x80000000u)
               ? *(const float*)(ws + WS_CC + (cf2 & 0x7fffffffu) + dim * 4)
               : *(const float*)((const char*)buffers + cf2 + dim * 4);
        s1c[j] = (cf1 & 0x80000000u)
               ? *(const float*)(ws + WS_CC + (cf1 & 0x7fffffffu) + dim * 4)
               : *(const float*)((const char*)buffers + cf1 + dim * 4);
      }
      bf16x8 t2f[4], rcf[4];
      #pragma unroll
      for (int kt = 0; kt < 4; ++kt){
        t2f[kt] = *(const bf16x8*)(th_wr + (rb + r16) * 128 + kt * 32 + koff);
        rcf[kt] = *(const bf16x8*)(ws + WS_HEAP + o2 + (kt * 32 + koff) * 2);
      }
      f32x4 ac2[5];
      #pragma unroll
      for (int p = 0; p < 5; ++p) ac2[p] = (f32x4){0.f, 0.f, 0.f, 0.f};
      #pragma unroll
      for (int p = 0; p < 5; ++p)
        #pragma unroll
        for (int kt = 0; kt < 4; ++kt){
          bf16x8 wlf = *(const bf16x8*)(ws + WS_WL + (((8 * p + w) * 4 + kt) * 64 + l) * 16);
          bf16x8 wtf = *(const bf16x8*)(ws + WS_WT + (((8 * p + w) * 4 + kt) * 64 + l) * 16);
          ac2[p] = __builtin_amdgcn_mfma_f32_16x16x32_bf16(rcf[kt], wlf, ac2[p], 0, 0, 0);
          ac2[p] = __builtin_amdgcn_mfma_f32_16x16x32_bf16(t2f[kt], wtf, ac2[p], 0, 0, 0);
        }
      #pragma unroll
      for (int j = 0; j < 4; ++j){
        int row_g = rb + 4 * hi + j;
        float gv  = ac2[0][j] + h2f(csq[0][j]);
        float iv  = ac2[1][j] + h2f(csq[1][j]);
        float f1v = ac2[2][j] + h2f(csq[2][j]);
        float f2v = ac2[3][j] + h2f(csq[3][j]);
        float ov  = ac2[4][j] + h2f(csq[4][j]);
        float cc = sigf(f1v) * s2c[j] + sigf(f2v) * s1c[j] + sigf(iv) * tanhf_(gv);
        float hh = sigf(ov) * tanhf_(cc);
        if (od0 >= 0){
          *(unsigned short*)(ws + WS_HEAP + (size_t)(1 + od0 * 64 + row_g) * 256 + dim * 2) = f2bf(hh);
          *(float*)(ws + WS_CC + ((size_t)(od0 * 64 + row_g) * 128 + dim) * 4) = cc;
        }
      }
      __syncthreads();
    }
  }

  // ---------- epilogue (own 16 rows) ----------
  for (int i = tid; i < 16 * 128; i += 512){
    int brow = rb + (i >> 7), dm = i & 127;
    unsigned src = *(const unsigned*)(ws + WS_OSRC + brow * 4);
    const unsigned short* p = (src & 0x80000000u)
        ? (const unsigned short*)(ws + WS_HEAP + (src & 0x7fffffffu) + dm * 2)
        : (const unsigned short*)(ws + WS_BUFH + src + dm * 2);
    out[brow * 128 + dm] = bf2f(*p);
  }
}

extern "C" void kernel_launch(void* const* d_in, const int* in_sizes, int n_in,
                              void* d_out, int out_size, void* d_ws, size_t ws_size,
                              hipStream_t stream){
  const float* buffers = (const float*)d_in[0];
  const int*   trans   = (const int*)d_in[1];
  const float* W_ih    = (const float*)d_in[2];
  const float* W_hh    = (const float*)d_in[3];
  const float* b_ih    = (const float*)d_in[4];
  const float* b_hh    = (const float*)d_in[5];
  const float* Wl      = (const float*)d_in[6];
  const float* bl      = (const float*)d_in[7];
  const float* Wr      = (const float*)d_in[8];
  const float* Wt      = (const float*)d_in[9];
  unsigned char* ws = (unsigned char*)d_ws;
  k0_sim   <<<dim3(1),    dim3(64),  0,      stream>>>(trans, ws);
  k1_prep  <<<dim3(2048), dim3(256), 0,      stream>>>(buffers, W_ih, W_hh, Wl, Wr, Wt, ws);
  k2_xs    <<<dim3(189),  dim3(256), 0,      stream>>>(b_ih, b_hh, ws);
  k2b_cs   <<<dim3(189),  dim3(256), 0,      stream>>>(bl, ws);
  k3_serial<<<dim3(4),    dim3(512), 131072, stream>>>(buffers, (float*)d_out, ws);
}